// Round 4
// baseline (36772.571 us; speedup 1.0000x reference)
//
#include <hip/hip_runtime.h>
#include <math.h>

// LSTMClassifier: B=32, S=256, E=256, H=512, 4 layers, softmax over S, FC->4.
//
// Structure:
//  - 8 groups (XCD-local under blockIdx%8 round-robin), each owns 4 batches.
//  - Per group: 32 WGs x 512 threads. WG owns 16 hidden units (64 gate rows).
//  - Weights persistent in VGPRs (lane = gate row, K sliced across 8 waves).
//  - Per-step pipeline: [prefetch x_{t+1} -> LDS] [x-part FMAs] [group-barrier
//    wait for h_t] [h-part FMAs] [LDS reduce] [finalize+store h] [release].
//    The barrier wait + h LLC round-trip hides under the x-part compute.
//  - ws layout (~41MB): WihT(4M) WhhT(4M) HA(16M) HB(16M) HCUR(512K) CNT MARR ZARR

#define S_LEN 256
#define NGATE 2048
#define HDIM  512

// ---------------- transpose [R][C] -> [C][R] ----------------
__global__ void transpose_rc(const float* __restrict__ in, float* __restrict__ out,
                             int R, int C) {
  __shared__ float tile[32][33];
  int cb = blockIdx.x * 32, rb = blockIdx.y * 32;
  int tx = threadIdx.x & 31, ty = threadIdx.x >> 5;  // 32x8
  #pragma unroll
  for (int i = ty; i < 32; i += 8)
    tile[i][tx] = in[(size_t)(rb + i) * C + (cb + tx)];
  __syncthreads();
  #pragma unroll
  for (int i = ty; i < 32; i += 8)
    out[(size_t)(cb + i) * R + (rb + tx)] = tile[tx][i];
}

__device__ __forceinline__ float sigm(float x) { return 1.0f / (1.0f + __expf(-x)); }
// fast tanh via hardware exp; clamp keeps e^{2x} finite (tanh(15)==1 in fp32)
__device__ __forceinline__ float ftanh(float x) {
  float e = __expf(2.0f * fminf(fmaxf(x, -15.0f), 15.0f));
  return (e - 1.0f) / (e + 1.0f);
}

// async global->LDS prefetch of one step's x slice for this wave.
// Legal global_load_lds sizes: 1,2,4,12,16 bytes.
// KIN=512: one 16B/lane xfer: lane l -> batch=l>>4, floats (l&15)*4..+3
// KIN=256: two  4B/lane xfers: i=l+64j -> batch=i>>5, float i&31
template <int KIN>
__device__ __forceinline__ void prefetch_x(const float* gbase, float* ldsdst, int lane) {
  if constexpr (KIN == 512) {
    const float* g = gbase + (size_t)(lane >> 4) * (S_LEN * KIN) + ((lane & 15) << 2);
    __builtin_amdgcn_global_load_lds((const __attribute__((address_space(1))) void*)g,
                                     (__attribute__((address_space(3))) void*)ldsdst,
                                     16, 0, 0);
  } else {
    #pragma unroll
    for (int j = 0; j < 2; ++j) {
      int i = lane + 64 * j;
      const float* g = gbase + (size_t)(i >> 5) * (S_LEN * KIN) + (i & 31);
      __builtin_amdgcn_global_load_lds((const __attribute__((address_space(1))) void*)g,
                                       (__attribute__((address_space(3))) void*)(ldsdst + j * 64),
                                       4, 0, 0);
    }
  }
}

// ---------------- fused LSTM layer ----------------
template <int KIN>
__global__ __launch_bounds__(512, 2) void lstm_layer_k(
    const float* __restrict__ xin,   // [32][256][KIN]
    const float* __restrict__ WihT,  // [KIN][2048]
    const float* __restrict__ WhhT,  // [512][2048]
    const float* __restrict__ bih,   // [2048]
    const float* __restrict__ bhh,   // [2048]
    float* __restrict__ hseq,        // [32][256][512]
    float* __restrict__ hcur,        // [2][32][512]
    unsigned* __restrict__ cnt)      // [8]
{
  constexpr int KXW = KIN / 8;  // x k-slice per wave (32 or 64)
  const int tid  = threadIdx.x;
  const int wave = tid >> 6;
  const int lane = tid & 63;
  const int g    = blockIdx.x & 7;   // group (== XCD under round-robin)
  const int wgrp = blockIdx.x >> 3;  // 0..31: which 16-unit slice
  const int gate = lane >> 4;
  const int ul   = lane & 15;
  const int row  = gate * HDIM + wgrp * 16 + ul;  // global gate row

  // persistent weights in registers (transposed layout -> coalesced loads)
  float wx[KXW], wh[64];
  {
    const float* p = WihT + (size_t)(wave * KXW) * NGATE + row;
    #pragma unroll
    for (int i = 0; i < KXW; i++) wx[i] = p[(size_t)i * NGATE];
    const float* q = WhhT + (size_t)(wave * 64) * NGATE + row;
    #pragma unroll
    for (int i = 0; i < 64; i++) wh[i] = q[(size_t)i * NGATE];
  }

  // finalize threads: tid<64 (wave 0), (u2,b2) = (tid>>2, tid&3)
  float bs0 = 0, bs1 = 0, bs2 = 0, bs3 = 0, c_state = 0.f;
  int u2 = 0, b2 = 0;
  if (tid < 64) {
    u2 = tid >> 2; b2 = tid & 3;
    int ug = wgrp * 16 + u2;
    bs0 = bih[0 * HDIM + ug] + bhh[0 * HDIM + ug];
    bs1 = bih[1 * HDIM + ug] + bhh[1 * HDIM + ug];
    bs2 = bih[2 * HDIM + ug] + bhh[2 * HDIM + ug];
    bs3 = bih[3 * HDIM + ug] + bhh[3 * HDIM + ug];
  }

  __shared__ float part[8][64][4];        // 8KB
  __shared__ float xbuf[2][8][256];       // 16KB, per-wave-private x staging

  unsigned* mycnt = cnt + g;
  const float* xwbase = xin + (size_t)(g * 4) * S_LEN * KIN + wave * KXW;

  // prime x_0
  prefetch_x<KIN>(xwbase, &xbuf[0][wave][0], lane);
  __syncthreads();  // drains vmcnt -> xbuf[0] valid

  for (int t = 0; t < S_LEN; ++t) {
    // ---- prefetch x_{t+1} (hazard-free: buffer parity consumed at t-1,
    //      separated from this issue by two vmcnt(0)-draining barriers) ----
    if (t + 1 < S_LEN)
      prefetch_x<KIN>(xwbase + (size_t)(t + 1) * KIN, &xbuf[(t + 1) & 1][wave][0], lane);

    // ---- x-part (independent of h_t): LDS broadcast reads ----
    const float* xb = &xbuf[t & 1][wave][0];
    float a0 = 0.f, a1 = 0.f, a2 = 0.f, a3 = 0.f;
    #pragma unroll
    for (int i = 0; i < KXW; i += 4) {
      float4 v0 = *(const float4*)(xb + 0 * KXW + i);
      float4 v1 = *(const float4*)(xb + 1 * KXW + i);
      float4 v2 = *(const float4*)(xb + 2 * KXW + i);
      float4 v3 = *(const float4*)(xb + 3 * KXW + i);
      a0 += wx[i]*v0.x + wx[i+1]*v0.y + wx[i+2]*v0.z + wx[i+3]*v0.w;
      a1 += wx[i]*v1.x + wx[i+1]*v1.y + wx[i+2]*v1.z + wx[i+3]*v1.w;
      a2 += wx[i]*v2.x + wx[i+1]*v2.y + wx[i+2]*v2.z + wx[i+3]*v2.w;
      a3 += wx[i]*v3.x + wx[i+1]*v3.y + wx[i+2]*v3.z + wx[i+3]*v3.w;
    }

    // ---- wait for h_t (producers of step t-1); hidden under x-part ----
    if (tid == 0) {
      const unsigned target = 32u * (unsigned)t;
      while (__hip_atomic_load(mycnt, __ATOMIC_ACQUIRE, __HIP_MEMORY_SCOPE_AGENT) < target)
        __builtin_amdgcn_s_sleep(1);
    }
    __syncthreads();

    // ---- h-part ----
    const float* h0 = hcur + ((size_t)(t & 1) * 32 + g * 4 + 0) * HDIM + wave * 64;
    const float* h1 = h0 + HDIM;
    const float* h2 = h1 + HDIM;
    const float* h3 = h2 + HDIM;
    #pragma unroll
    for (int i = 0; i < 64; i += 4) {
      float4 v0 = *(const float4*)(h0 + i);
      float4 v1 = *(const float4*)(h1 + i);
      float4 v2 = *(const float4*)(h2 + i);
      float4 v3 = *(const float4*)(h3 + i);
      a0 += wh[i]*v0.x + wh[i+1]*v0.y + wh[i+2]*v0.z + wh[i+3]*v0.w;
      a1 += wh[i]*v1.x + wh[i+1]*v1.y + wh[i+2]*v1.z + wh[i+3]*v1.w;
      a2 += wh[i]*v2.x + wh[i+1]*v2.y + wh[i+2]*v2.z + wh[i+3]*v2.w;
      a3 += wh[i]*v3.x + wh[i+1]*v3.y + wh[i+2]*v3.z + wh[i+3]*v3.w;
    }

    *(float4*)&part[wave][lane][0] = make_float4(a0, a1, a2, a3);
    __syncthreads();

    // ---- finalize: gates, state update, h store ----
    if (tid < 64) {
      float s0 = bs0, s1 = bs1, s2 = bs2, s3 = bs3;
      #pragma unroll
      for (int w = 0; w < 8; w++) {
        s0 += part[w][u2][b2];
        s1 += part[w][16 + u2][b2];
        s2 += part[w][32 + u2][b2];
        s3 += part[w][48 + u2][b2];
      }
      float iv = sigm(s0), fv = sigm(s1), gv = ftanh(s2), ov = sigm(s3);
      c_state = fv * c_state + iv * gv;
      float hv = ov * ftanh(c_state);
      int ug = wgrp * 16 + u2;
      int gb = g * 4 + b2;  // global batch
      hcur[((size_t)((t + 1) & 1) * 32 + gb) * HDIM + ug] = hv;
      hseq[((size_t)gb * S_LEN + t) * HDIM + ug] = hv;
    }

    // ---- release: h_t+1 published (tid0 is in wave 0 = the storing wave) ----
    if (tid == 0)
      __hip_atomic_fetch_add(mycnt, 1u, __ATOMIC_RELEASE, __HIP_MEMORY_SCOPE_AGENT);
    // no trailing barrier needed: next iteration's part-store is preceded by
    // the barrier-wait __syncthreads, which wave0 joins only after reading part.
  }
}

// ---------------- softmax-over-S stats per (b,h) ----------------
__global__ void colstats_k(const float* __restrict__ h3,
                           float* __restrict__ marr, float* __restrict__ zarr) {
  int j = blockIdx.x * 256 + threadIdx.x;  // 32*512 = 16384
  int b = j >> 9, h = j & 511;
  const float* p = h3 + (size_t)b * S_LEN * HDIM + h;
  float m = -1e30f, z = 0.f;
  for (int t = 0; t < S_LEN; ++t) {
    float v = p[(size_t)t * HDIM];
    float nm = fmaxf(m, v);
    z = z * __expf(m - nm) + __expf(v - nm);
    m = nm;
  }
  marr[j] = m; zarr[j] = z;
}

// ---------------- output: probs @ Wfc^T + bfc ----------------
__global__ void out_k(const float* __restrict__ h3, const float* __restrict__ marr,
                      const float* __restrict__ zarr, const float* __restrict__ Wfc,
                      const float* __restrict__ bfc, float* __restrict__ out) {
  int bt = blockIdx.x;  // 8192 = [b][t]
  int b = bt >> 8;
  int lane = threadIdx.x;  // 64
  const float* hp = h3 + (size_t)bt * HDIM;
  const float* mp = marr + b * HDIM;
  const float* zp = zarr + b * HDIM;
  float a0 = 0, a1 = 0, a2 = 0, a3 = 0;
  #pragma unroll
  for (int i = 0; i < 8; i++) {
    int h = lane * 8 + i;
    float p = __expf(hp[h] - mp[h]) / zp[h];
    a0 += p * Wfc[0 * HDIM + h];
    a1 += p * Wfc[1 * HDIM + h];
    a2 += p * Wfc[2 * HDIM + h];
    a3 += p * Wfc[3 * HDIM + h];
  }
  #pragma unroll
  for (int off = 32; off; off >>= 1) {
    a0 += __shfl_down(a0, off);
    a1 += __shfl_down(a1, off);
    a2 += __shfl_down(a2, off);
    a3 += __shfl_down(a3, off);
  }
  if (lane == 0) {
    float* o = out + (size_t)bt * 4;
    o[0] = a0 + bfc[0]; o[1] = a1 + bfc[1]; o[2] = a2 + bfc[2]; o[3] = a3 + bfc[3];
  }
}

extern "C" void kernel_launch(void* const* d_in, const int* in_sizes, int n_in,
                              void* d_out, int out_size, void* d_ws, size_t ws_size,
                              hipStream_t stream) {
  const float* x    = (const float*)d_in[0];
  const float* Wih0 = (const float*)d_in[1];
  const float* WihR = (const float*)d_in[2];
  const float* Whh  = (const float*)d_in[3];
  const float* bih  = (const float*)d_in[4];
  const float* bhh  = (const float*)d_in[5];
  const float* Wfc  = (const float*)d_in[6];
  const float* bfc  = (const float*)d_in[7];
  float* out = (float*)d_out;

  char* ws = (char*)d_ws;
  const size_t MB = 1024 * 1024;
  float*    WT_IH = (float*)(ws);
  float*    WT_HH = (float*)(ws + 4 * MB);
  float*    HA    = (float*)(ws + 8 * MB);
  float*    HB    = (float*)(ws + 24 * MB);
  float*    HCUR  = (float*)(ws + 40 * MB);                 // 4 x 2*32*512 f32 = 512KB
  unsigned* CNT   = (unsigned*)(ws + 40 * MB + 512 * 1024); // 32 uints (pad 4KB)
  float*    MARR  = (float*)(ws + 40 * MB + 516 * 1024);    // 64KB
  float*    ZARR  = (float*)(ws + 40 * MB + 580 * 1024);    // 64KB

  // zero h state + barrier counters (ws is poisoned 0xAA before every call)
  (void)hipMemsetAsync(HCUR, 0, 512 * 1024 + 4096, stream);

  for (int l = 0; l < 4; ++l) {
    const int kin = (l == 0) ? 256 : 512;
    const float* wih = (l == 0) ? Wih0 : (WihR + (size_t)(l - 1) * NGATE * HDIM);
    const float* whh = Whh + (size_t)l * NGATE * HDIM;

    transpose_rc<<<dim3(kin / 32, NGATE / 32), 256, 0, stream>>>(wih, WT_IH, NGATE, kin);
    transpose_rc<<<dim3(HDIM / 32, NGATE / 32), 256, 0, stream>>>(whh, WT_HH, NGATE, HDIM);

    const float* xin = (l == 0) ? x : ((l & 1) ? HA : HB);
    float* hout = ((l & 1) == 0) ? HA : HB;
    float* hc = HCUR + (size_t)l * 2 * 32 * HDIM;
    unsigned* cnt = CNT + l * 8;

    if (l == 0)
      lstm_layer_k<256><<<256, 512, 0, stream>>>(x, WT_IH, WT_HH, bih + l * NGATE,
                                                 bhh + l * NGATE, hout, hc, cnt);
    else
      lstm_layer_k<512><<<256, 512, 0, stream>>>(xin, WT_IH, WT_HH, bih + l * NGATE,
                                                 bhh + l * NGATE, hout, hc, cnt);
  }

  // layer 3 writes HB
  colstats_k<<<64, 256, 0, stream>>>(HB, MARR, ZARR);
  out_k<<<8192, 64, 0, stream>>>(HB, MARR, ZARR, Wfc, bfc, out);
}

// Round 5
// 35791.782 us; speedup vs baseline: 1.0274x; 1.0274x over previous
//
#include <hip/hip_runtime.h>
#include <math.h>

// LSTMClassifier: B=32, S=256, E=256, H=512, 4 layers, softmax over S, FC->4.
//
// Structure:
//  - 8 groups (XCD-local under blockIdx%8 round-robin), each owns 4 batches.
//  - Per group: 32 WGs x 512 threads. WG owns 16 hidden units (64 gate rows).
//  - Weights persistent in VGPRs (lane = gate row, K sliced across 8 waves).
//    R4 fix: __launch_bounds__(512,1) — the (512,2) bound capped the allocator
//    at 128 VGPRs, evicting the 128 weight regs -> 19GB/dispatch refetch, 44ms.
//  - Per-step pipeline: [prefetch x_{t+1} -> LDS] [x-part FMAs] [group-barrier
//    wait for h_t] [h-part FMAs] [LDS reduce] [finalize+store h] [release].
//  - Barrier counters padded to 128B/group (R4: kill cross-XCD false sharing).
//  - ws layout (~41MB): WihT(4M) WhhT(4M) HA(16M) HB(16M) HCUR(512K) CNT MARR ZARR

#define S_LEN 256
#define NGATE 2048
#define HDIM  512
#define CNT_STRIDE 32  // uints; 128B per group counter line

// ---------------- transpose [R][C] -> [C][R] ----------------
__global__ void transpose_rc(const float* __restrict__ in, float* __restrict__ out,
                             int R, int C) {
  __shared__ float tile[32][33];
  int cb = blockIdx.x * 32, rb = blockIdx.y * 32;
  int tx = threadIdx.x & 31, ty = threadIdx.x >> 5;  // 32x8
  #pragma unroll
  for (int i = ty; i < 32; i += 8)
    tile[i][tx] = in[(size_t)(rb + i) * C + (cb + tx)];
  __syncthreads();
  #pragma unroll
  for (int i = ty; i < 32; i += 8)
    out[(size_t)(cb + i) * R + (rb + tx)] = tile[tx][i];
}

__device__ __forceinline__ float sigm(float x) { return 1.0f / (1.0f + __expf(-x)); }
// fast tanh via hardware exp; clamp keeps e^{2x} finite (tanh(15)==1 in fp32)
__device__ __forceinline__ float ftanh(float x) {
  float e = __expf(2.0f * fminf(fmaxf(x, -15.0f), 15.0f));
  return (e - 1.0f) / (e + 1.0f);
}

// async global->LDS prefetch of one step's x slice for this wave.
// Legal global_load_lds sizes: 1,2,4,12,16 bytes.
// KIN=512: one 16B/lane xfer: lane l -> batch=l>>4, floats (l&15)*4..+3
// KIN=256: two  4B/lane xfers: i=l+64j -> batch=i>>5, float i&31
template <int KIN>
__device__ __forceinline__ void prefetch_x(const float* gbase, float* ldsdst, int lane) {
  if constexpr (KIN == 512) {
    const float* g = gbase + (size_t)(lane >> 4) * (S_LEN * KIN) + ((lane & 15) << 2);
    __builtin_amdgcn_global_load_lds((const __attribute__((address_space(1))) void*)g,
                                     (__attribute__((address_space(3))) void*)ldsdst,
                                     16, 0, 0);
  } else {
    #pragma unroll
    for (int j = 0; j < 2; ++j) {
      int i = lane + 64 * j;
      const float* g = gbase + (size_t)(i >> 5) * (S_LEN * KIN) + (i & 31);
      __builtin_amdgcn_global_load_lds((const __attribute__((address_space(1))) void*)g,
                                       (__attribute__((address_space(3))) void*)(ldsdst + j * 64),
                                       4, 0, 0);
    }
  }
}

// ---------------- fused LSTM layer ----------------
template <int KIN>
__global__ __launch_bounds__(512, 1) void lstm_layer_k(
    const float* __restrict__ xin,   // [32][256][KIN]
    const float* __restrict__ WihT,  // [KIN][2048]
    const float* __restrict__ WhhT,  // [512][2048]
    const float* __restrict__ bih,   // [2048]
    const float* __restrict__ bhh,   // [2048]
    float* __restrict__ hseq,        // [32][256][512]
    float* __restrict__ hcur,        // [2][32][512]
    unsigned* __restrict__ cnt)      // [8*CNT_STRIDE]
{
  constexpr int KXW = KIN / 8;  // x k-slice per wave (32 or 64)
  const int tid  = threadIdx.x;
  const int wave = tid >> 6;
  const int lane = tid & 63;
  const int g    = blockIdx.x & 7;   // group (== XCD under round-robin)
  const int wgrp = blockIdx.x >> 3;  // 0..31: which 16-unit slice
  const int gate = lane >> 4;
  const int ul   = lane & 15;
  const int row  = gate * HDIM + wgrp * 16 + ul;  // global gate row

  // persistent weights in registers (transposed layout -> coalesced loads)
  float wx[KXW], wh[64];
  {
    const float* p = WihT + (size_t)(wave * KXW) * NGATE + row;
    #pragma unroll
    for (int i = 0; i < KXW; i++) wx[i] = p[(size_t)i * NGATE];
    const float* q = WhhT + (size_t)(wave * 64) * NGATE + row;
    #pragma unroll
    for (int i = 0; i < 64; i++) wh[i] = q[(size_t)i * NGATE];
  }

  // finalize threads: tid<64 (wave 0), (u2,b2) = (tid>>2, tid&3)
  float bs0 = 0, bs1 = 0, bs2 = 0, bs3 = 0, c_state = 0.f;
  int u2 = 0, b2 = 0;
  if (tid < 64) {
    u2 = tid >> 2; b2 = tid & 3;
    int ug = wgrp * 16 + u2;
    bs0 = bih[0 * HDIM + ug] + bhh[0 * HDIM + ug];
    bs1 = bih[1 * HDIM + ug] + bhh[1 * HDIM + ug];
    bs2 = bih[2 * HDIM + ug] + bhh[2 * HDIM + ug];
    bs3 = bih[3 * HDIM + ug] + bhh[3 * HDIM + ug];
  }

  __shared__ float part[8][64][4];        // 8KB
  __shared__ float xbuf[2][8][256];       // 16KB, per-wave-private x staging

  unsigned* mycnt = cnt + g * CNT_STRIDE;
  const float* xwbase = xin + (size_t)(g * 4) * S_LEN * KIN + wave * KXW;

  // prime x_0
  prefetch_x<KIN>(xwbase, &xbuf[0][wave][0], lane);
  __syncthreads();  // drains vmcnt -> xbuf[0] valid

  for (int t = 0; t < S_LEN; ++t) {
    // ---- prefetch x_{t+1} (hazard-free: buffer parity consumed at t-1,
    //      separated from this issue by two vmcnt(0)-draining barriers) ----
    if (t + 1 < S_LEN)
      prefetch_x<KIN>(xwbase + (size_t)(t + 1) * KIN, &xbuf[(t + 1) & 1][wave][0], lane);

    // ---- x-part (independent of h_t): LDS broadcast reads ----
    const float* xb = &xbuf[t & 1][wave][0];
    float a0 = 0.f, a1 = 0.f, a2 = 0.f, a3 = 0.f;
    #pragma unroll
    for (int i = 0; i < KXW; i += 4) {
      float4 v0 = *(const float4*)(xb + 0 * KXW + i);
      float4 v1 = *(const float4*)(xb + 1 * KXW + i);
      float4 v2 = *(const float4*)(xb + 2 * KXW + i);
      float4 v3 = *(const float4*)(xb + 3 * KXW + i);
      a0 += wx[i]*v0.x + wx[i+1]*v0.y + wx[i+2]*v0.z + wx[i+3]*v0.w;
      a1 += wx[i]*v1.x + wx[i+1]*v1.y + wx[i+2]*v1.z + wx[i+3]*v1.w;
      a2 += wx[i]*v2.x + wx[i+1]*v2.y + wx[i+2]*v2.z + wx[i+3]*v2.w;
      a3 += wx[i]*v3.x + wx[i+1]*v3.y + wx[i+2]*v3.z + wx[i+3]*v3.w;
    }

    // ---- wait for h_t (producers of step t-1); hidden under x-part ----
    if (tid == 0) {
      const unsigned target = 32u * (unsigned)t;
      while (__hip_atomic_load(mycnt, __ATOMIC_ACQUIRE, __HIP_MEMORY_SCOPE_AGENT) < target)
        __builtin_amdgcn_s_sleep(1);
    }
    __syncthreads();

    // ---- h-part ----
    const float* h0 = hcur + ((size_t)(t & 1) * 32 + g * 4 + 0) * HDIM + wave * 64;
    const float* h1 = h0 + HDIM;
    const float* h2 = h1 + HDIM;
    const float* h3 = h2 + HDIM;
    #pragma unroll
    for (int i = 0; i < 64; i += 4) {
      float4 v0 = *(const float4*)(h0 + i);
      float4 v1 = *(const float4*)(h1 + i);
      float4 v2 = *(const float4*)(h2 + i);
      float4 v3 = *(const float4*)(h3 + i);
      a0 += wh[i]*v0.x + wh[i+1]*v0.y + wh[i+2]*v0.z + wh[i+3]*v0.w;
      a1 += wh[i]*v1.x + wh[i+1]*v1.y + wh[i+2]*v1.z + wh[i+3]*v1.w;
      a2 += wh[i]*v2.x + wh[i+1]*v2.y + wh[i+2]*v2.z + wh[i+3]*v2.w;
      a3 += wh[i]*v3.x + wh[i+1]*v3.y + wh[i+2]*v3.z + wh[i+3]*v3.w;
    }

    *(float4*)&part[wave][lane][0] = make_float4(a0, a1, a2, a3);
    __syncthreads();

    // ---- finalize: gates, state update, h store ----
    if (tid < 64) {
      float s0 = bs0, s1 = bs1, s2 = bs2, s3 = bs3;
      #pragma unroll
      for (int w = 0; w < 8; w++) {
        s0 += part[w][u2][b2];
        s1 += part[w][16 + u2][b2];
        s2 += part[w][32 + u2][b2];
        s3 += part[w][48 + u2][b2];
      }
      float iv = sigm(s0), fv = sigm(s1), gv = ftanh(s2), ov = sigm(s3);
      c_state = fv * c_state + iv * gv;
      float hv = ov * ftanh(c_state);
      int ug = wgrp * 16 + u2;
      int gb = g * 4 + b2;  // global batch
      hcur[((size_t)((t + 1) & 1) * 32 + gb) * HDIM + ug] = hv;
      hseq[((size_t)gb * S_LEN + t) * HDIM + ug] = hv;
    }

    // ---- release: h_t+1 published (tid0 is in wave 0 = the storing wave) ----
    if (tid == 0)
      __hip_atomic_fetch_add(mycnt, 1u, __ATOMIC_RELEASE, __HIP_MEMORY_SCOPE_AGENT);
    // no trailing barrier needed: next iteration's part-store is preceded by
    // the barrier-wait __syncthreads, which wave0 joins only after reading part.
  }
}

// ---------------- softmax-over-S stats per (b,h) ----------------
__global__ void colstats_k(const float* __restrict__ h3,
                           float* __restrict__ marr, float* __restrict__ zarr) {
  int j = blockIdx.x * 256 + threadIdx.x;  // 32*512 = 16384
  int b = j >> 9, h = j & 511;
  const float* p = h3 + (size_t)b * S_LEN * HDIM + h;
  float m = -1e30f, z = 0.f;
  for (int t = 0; t < S_LEN; ++t) {
    float v = p[(size_t)t * HDIM];
    float nm = fmaxf(m, v);
    z = z * __expf(m - nm) + __expf(v - nm);
    m = nm;
  }
  marr[j] = m; zarr[j] = z;
}

// ---------------- output: probs @ Wfc^T + bfc ----------------
__global__ void out_k(const float* __restrict__ h3, const float* __restrict__ marr,
                      const float* __restrict__ zarr, const float* __restrict__ Wfc,
                      const float* __restrict__ bfc, float* __restrict__ out) {
  int bt = blockIdx.x;  // 8192 = [b][t]
  int b = bt >> 8;
  int lane = threadIdx.x;  // 64
  const float* hp = h3 + (size_t)bt * HDIM;
  const float* mp = marr + b * HDIM;
  const float* zp = zarr + b * HDIM;
  float a0 = 0, a1 = 0, a2 = 0, a3 = 0;
  #pragma unroll
  for (int i = 0; i < 8; i++) {
    int h = lane * 8 + i;
    float p = __expf(hp[h] - mp[h]) / zp[h];
    a0 += p * Wfc[0 * HDIM + h];
    a1 += p * Wfc[1 * HDIM + h];
    a2 += p * Wfc[2 * HDIM + h];
    a3 += p * Wfc[3 * HDIM + h];
  }
  #pragma unroll
  for (int off = 32; off; off >>= 1) {
    a0 += __shfl_down(a0, off);
    a1 += __shfl_down(a1, off);
    a2 += __shfl_down(a2, off);
    a3 += __shfl_down(a3, off);
  }
  if (lane == 0) {
    float* o = out + (size_t)bt * 4;
    o[0] = a0 + bfc[0]; o[1] = a1 + bfc[1]; o[2] = a2 + bfc[2]; o[3] = a3 + bfc[3];
  }
}

extern "C" void kernel_launch(void* const* d_in, const int* in_sizes, int n_in,
                              void* d_out, int out_size, void* d_ws, size_t ws_size,
                              hipStream_t stream) {
  const float* x    = (const float*)d_in[0];
  const float* Wih0 = (const float*)d_in[1];
  const float* WihR = (const float*)d_in[2];
  const float* Whh  = (const float*)d_in[3];
  const float* bih  = (const float*)d_in[4];
  const float* bhh  = (const float*)d_in[5];
  const float* Wfc  = (const float*)d_in[6];
  const float* bfc  = (const float*)d_in[7];
  float* out = (float*)d_out;

  char* ws = (char*)d_ws;
  const size_t MB = 1024 * 1024;
  float*    WT_IH = (float*)(ws);
  float*    WT_HH = (float*)(ws + 4 * MB);
  float*    HA    = (float*)(ws + 8 * MB);
  float*    HB    = (float*)(ws + 24 * MB);
  float*    HCUR  = (float*)(ws + 40 * MB);                 // 4 x 2*32*512 f32 = 512KB
  unsigned* CNT   = (unsigned*)(ws + 40 * MB + 512 * 1024); // 4 layers x 8 x 32 uints = 4KB
  float*    MARR  = (float*)(ws + 40 * MB + 516 * 1024);    // 64KB
  float*    ZARR  = (float*)(ws + 40 * MB + 580 * 1024);    // 64KB

  // zero h state + barrier counters (ws is poisoned 0xAA before every call)
  (void)hipMemsetAsync(HCUR, 0, 512 * 1024 + 4096, stream);

  for (int l = 0; l < 4; ++l) {
    const int kin = (l == 0) ? 256 : 512;
    const float* wih = (l == 0) ? Wih0 : (WihR + (size_t)(l - 1) * NGATE * HDIM);
    const float* whh = Whh + (size_t)l * NGATE * HDIM;

    transpose_rc<<<dim3(kin / 32, NGATE / 32), 256, 0, stream>>>(wih, WT_IH, NGATE, kin);
    transpose_rc<<<dim3(HDIM / 32, NGATE / 32), 256, 0, stream>>>(whh, WT_HH, NGATE, HDIM);

    const float* xin = (l == 0) ? x : ((l & 1) ? HA : HB);
    float* hout = ((l & 1) == 0) ? HA : HB;
    float* hc = HCUR + (size_t)l * 2 * 32 * HDIM;
    unsigned* cnt = CNT + l * 8 * CNT_STRIDE;

    if (l == 0)
      lstm_layer_k<256><<<256, 512, 0, stream>>>(x, WT_IH, WT_HH, bih + l * NGATE,
                                                 bhh + l * NGATE, hout, hc, cnt);
    else
      lstm_layer_k<512><<<256, 512, 0, stream>>>(xin, WT_IH, WT_HH, bih + l * NGATE,
                                                 bhh + l * NGATE, hout, hc, cnt);
  }

  // layer 3 writes HB
  colstats_k<<<64, 256, 0, stream>>>(HB, MARR, ZARR);
  out_k<<<8192, 64, 0, stream>>>(HB, MARR, ZARR, Wfc, bfc, out);
}